// Round 1
// baseline (910.260 us; speedup 1.0000x reference)
//
#include <hip/hip_runtime.h>
#include <hip/hip_bf16.h>

// Quantized int8 3x3 conv, stride 1, VALID.
//   input  [32,128,56,56] int8 (delivered as int32 buffer)
//   weight [256,128,3,3]  int8 (delivered as int32 buffer)
//   bias   [256] f32
//   out    [32,256,54,54] f32
//
// out = 1e-4 * ( dot(a,b) - 3*sum(a) - 7*sum(b) + 1152*21 ) + bq
// bq = clamp(rint(bias/1e-4)) * 1e-4   (round half-even == jnp.round)

#define N_B   32
#define C_IN  128
#define H_IN  56
#define W_IN  56
#define C_OUT 256
#define H_OUT 54
#define W_OUT 54
#define K_TOT 1152   // 128*9

static __device__ __forceinline__ int dot4(int a, int b, int c) {
#if __has_builtin(__builtin_amdgcn_sdot4)
  return __builtin_amdgcn_sdot4(a, b, c, false);
#else
  signed char a0 = (signed char)a, a1 = (signed char)(a >> 8),
              a2 = (signed char)(a >> 16), a3 = (signed char)(a >> 24);
  signed char b0 = (signed char)b, b1 = (signed char)(b >> 8),
              b2 = (signed char)(b >> 16), b3 = (signed char)(b >> 24);
  return c + a0 * b0 + a1 * b1 + a2 * b2 + a3 * b3;
#endif
}

// ---------------- weight repack: OIHW(int32) -> wp[co][tap][ci] i8, wsum, bq
__global__ void repack_w(const int* __restrict__ w, const float* __restrict__ bias,
                         signed char* __restrict__ wp, int* __restrict__ wsum,
                         float* __restrict__ bq) {
  int co = blockIdx.x;    // 256
  int ci = threadIdx.x;   // 128
  const int* wrow = w + (size_t)co * K_TOT + (size_t)ci * 9;
  int s = 0;
  signed char vals[9];
#pragma unroll
  for (int t = 0; t < 9; ++t) { int v = wrow[t]; vals[t] = (signed char)v; s += v; }
#pragma unroll
  for (int t = 0; t < 9; ++t) wp[(size_t)co * K_TOT + t * 128 + ci] = vals[t];

  __shared__ int red[128];
  red[ci] = s;
  __syncthreads();
  for (int off = 64; off > 0; off >>= 1) {
    if (ci < off) red[ci] += red[ci + off];
    __syncthreads();
  }
  if (ci == 0) {
    wsum[co] = red[0];
    float r = rintf(bias[co] / 0.0001f);               // round half-even
    r = fminf(fmaxf(r, -2147483648.0f), 2147483647.0f); // clamp to i32 range
    bq[co] = r * 0.0001f;
  }
}

// ---------------- input repack: NCHW(int32) -> NHWC int8
__global__ void repack_in(const int* __restrict__ in, signed char* __restrict__ ip) {
  int h  = blockIdx.x;    // 56
  int n  = blockIdx.y;    // 32
  int ci = threadIdx.x;   // 128
  const int4* src = (const int4*)(in + (((size_t)n * C_IN + ci) * H_IN + h) * W_IN);
  signed char* dst = ip + (((size_t)n * H_IN + h) * W_IN) * C_IN + ci;
#pragma unroll
  for (int i = 0; i < 14; ++i) {
    int4 v = src[i];
    dst[(size_t)(i * 4 + 0) * C_IN] = (signed char)v.x;
    dst[(size_t)(i * 4 + 1) * C_IN] = (signed char)v.y;
    dst[(size_t)(i * 4 + 2) * C_IN] = (signed char)v.z;
    dst[(size_t)(i * 4 + 3) * C_IN] = (signed char)v.w;
  }
}

// ---------------- per-pixel channel sums rs[n][h][w] = sum_ci ip
__global__ void rowsum_k(const signed char* __restrict__ ip, int* __restrict__ rs) {
  int h = blockIdx.x;     // 56
  int n = blockIdx.y;     // 32
  int w = threadIdx.x;    // 64, 56 active
  if (w >= W_IN) return;
  const int4* p = (const int4*)(ip + (((size_t)n * H_IN + h) * W_IN + w) * C_IN);
  int s = 0;
#pragma unroll
  for (int i = 0; i < 8; ++i) {
    int4 v = p[i];
    s = dot4(v.x, 0x01010101, s);
    s = dot4(v.y, 0x01010101, s);
    s = dot4(v.z, 0x01010101, s);
    s = dot4(v.w, 0x01010101, s);
  }
  rs[((size_t)n * H_IN + h) * W_IN + w] = s;
}

// ---------------- main conv
// grid (y=54, n=32, cog=16), block 256. lane = x (54 active), wave owns 4 couts.
__launch_bounds__(256)
__global__ void conv_main(const signed char* __restrict__ ip,
                          const signed char* __restrict__ wp,
                          const int* __restrict__ rs,
                          const int* __restrict__ wsum,
                          const float* __restrict__ bq,
                          float* __restrict__ out) {
  int y   = blockIdx.x;
  int n   = blockIdx.y;
  int cog = blockIdx.z;
  int tid  = threadIdx.x;
  int lane = tid & 63;
  int wv   = tid >> 6;            // 0..3
  int x = lane < W_OUT ? lane : (W_OUT - 1);
  bool active = lane < W_OUT;
  int co0 = cog * 16 + wv * 4;

  // transposed LDS tile: [kh][ci-chunk(8 x int4)][w], +1 pad breaks bank aliasing
  __shared__ int4 a_lds[3][8][57];

  const signed char* ipn = ip + ((size_t)n * H_IN + y) * W_IN * C_IN;
  for (int i = tid; i < 3 * 448; i += 256) {       // 448 int4 per row
    int row = i / 448;
    int rem = i - row * 448;
    int w = rem >> 3, c = rem & 7;
    int4 v = *(const int4*)(ipn + (size_t)row * W_IN * C_IN + w * C_IN + c * 16);
    a_lds[row][c][w] = v;
  }
  __syncthreads();

  // receptive-field input sum (per output pixel, co-independent)
  const int* rsrow = rs + ((size_t)n * H_IN + y) * W_IN;
  int asum = 0;
#pragma unroll
  for (int kh = 0; kh < 3; ++kh)
#pragma unroll
    for (int kw = 0; kw < 3; ++kw)
      asum += rsrow[kh * W_IN + x + kw];

  int acc[4] = {0, 0, 0, 0};
  const signed char* wpc = wp + (size_t)co0 * K_TOT;
#pragma unroll
  for (int kh = 0; kh < 3; ++kh) {
#pragma unroll
    for (int kw = 0; kw < 3; ++kw) {
      int tap = kh * 3 + kw;
#pragma unroll
      for (int c = 0; c < 8; ++c) {
        int4 a = a_lds[kh][c][x + kw];
#pragma unroll
        for (int r = 0; r < 4; ++r) {
          int4 b = *(const int4*)(wpc + (size_t)r * K_TOT + tap * 128 + c * 16);
          acc[r] = dot4(a.x, b.x, acc[r]);
          acc[r] = dot4(a.y, b.y, acc[r]);
          acc[r] = dot4(a.z, b.z, acc[r]);
          acc[r] = dot4(a.w, b.w, acc[r]);
        }
      }
    }
  }

  if (active) {
    const int CORR = K_TOT * 21;   // K*IZ*WZ
    const float SS = 0.01f * 0.01f;
    float* o = out + (((size_t)(n * C_OUT + co0)) * H_OUT + y) * W_OUT + x;
#pragma unroll
    for (int r = 0; r < 4; ++r) {
      int v = acc[r] - 3 * asum - 7 * wsum[co0 + r] + CORR;
      o[(size_t)r * H_OUT * W_OUT] = (float)v * SS + bq[co0 + r];
    }
  }
}

// ---------------- fallback (tiny ws): naive direct conv, correct but slow
__global__ void conv_naive(const int* __restrict__ in, const int* __restrict__ w,
                           const float* __restrict__ bias, float* __restrict__ out) {
  size_t idx = (size_t)blockIdx.x * 256 + threadIdx.x;
  size_t total = (size_t)N_B * C_OUT * H_OUT * W_OUT;
  if (idx >= total) return;
  int x = idx % W_OUT; size_t t = idx / W_OUT;
  int y = t % H_OUT; t /= H_OUT;
  int co = t % C_OUT; int n = (int)(t / C_OUT);
  int acc = 0;
  for (int ci = 0; ci < C_IN; ++ci) {
    const int* ib = in + (((size_t)n * C_IN + ci) * H_IN + y) * W_IN + x;
    const int* wb = w + (((size_t)co * C_IN + ci) * 3) * 3;
    for (int kh = 0; kh < 3; ++kh)
      for (int kw = 0; kw < 3; ++kw)
        acc += (ib[kh * W_IN + kw] - 7) * (wb[kh * 3 + kw] - 3);
  }
  float r = rintf(bias[co] / 0.0001f);
  r = fminf(fmaxf(r, -2147483648.0f), 2147483647.0f);
  out[idx] = (float)acc * (0.01f * 0.01f) + r * 0.0001f;
}

extern "C" void kernel_launch(void* const* d_in, const int* in_sizes, int n_in,
                              void* d_out, int out_size, void* d_ws, size_t ws_size,
                              hipStream_t stream) {
  const int*   in   = (const int*)d_in[0];
  const int*   w    = (const int*)d_in[1];
  const float* bias = (const float*)d_in[2];
  float*       out  = (float*)d_out;

  // ws layout (16B-aligned chunks)
  const size_t WP_OFF  = 0;                       // 256*1152 i8      = 294912
  const size_t IP_OFF  = 294912;                  // 32*56*56*128 i8  = 12845056
  const size_t RS_OFF  = IP_OFF + 12845056;       // 32*56*56 i32     = 401408
  const size_t WS_OFF  = RS_OFF + 401408;         // 256 i32
  const size_t BQ_OFF  = WS_OFF + 1024;           // 256 f32
  const size_t NEED    = BQ_OFF + 1024;

  if (ws_size >= NEED) {
    char* ws = (char*)d_ws;
    signed char* wp   = (signed char*)(ws + WP_OFF);
    signed char* ip   = (signed char*)(ws + IP_OFF);
    int*         rs   = (int*)(ws + RS_OFF);
    int*         wsum = (int*)(ws + WS_OFF);
    float*       bq   = (float*)(ws + BQ_OFF);

    repack_w<<<C_OUT, 128, 0, stream>>>(w, bias, wp, wsum, bq);
    repack_in<<<dim3(H_IN, N_B), 128, 0, stream>>>(in, ip);
    rowsum_k<<<dim3(H_IN, N_B), 64, 0, stream>>>(ip, rs);
    conv_main<<<dim3(H_OUT, N_B, 16), 256, 0, stream>>>(ip, wp, rs, wsum, bq, out);
  } else {
    size_t total = (size_t)N_B * C_OUT * H_OUT * W_OUT;
    conv_naive<<<(total + 255) / 256, 256, 0, stream>>>(in, w, bias, out);
  }
}

// Round 2
// 99.667 us; speedup vs baseline: 9.1330x; 9.1330x over previous
//
#include <hip/hip_runtime.h>
#include <hip/hip_bf16.h>

// Quantized int8 3x3 conv via implicit-im2col MFMA (mfma_i32_16x16x64_i8).
// out = 1e-4*(dot - 3*asum_px - 7*wsum_co + 24192) + bq
//     = 1e-4*dot + asumf[px] + bconst[co]

#define N_B   32
#define C_IN  128
#define H_IN  56
#define W_IN  56
#define C_OUT 256
#define H_OUT 54
#define W_OUT 54
#define K_TOT 1152
#define NPX   (N_B * H_OUT * W_OUT)   // 93312
#define PXROW (H_OUT * W_OUT)         // 2916

using i32x4 = __attribute__((ext_vector_type(4))) int;

static __device__ __forceinline__ int dot4(int a, int b, int c) {
#if __has_builtin(__builtin_amdgcn_sdot4)
  return __builtin_amdgcn_sdot4(a, b, c, false);
#else
  signed char a0 = (signed char)a, a1 = (signed char)(a >> 8),
              a2 = (signed char)(a >> 16), a3 = (signed char)(a >> 24);
  signed char b0 = (signed char)b, b1 = (signed char)(b >> 8),
              b2 = (signed char)(b >> 16), b3 = (signed char)(b >> 24);
  return c + a0 * b0 + a1 * b1 + a2 * b2 + a3 * b3;
#endif
}

__device__ __forceinline__ void gload16(const void* g, void* l) {
  __builtin_amdgcn_global_load_lds(
      (const __attribute__((address_space(1))) void*)g,
      (__attribute__((address_space(3))) void*)l, 16, 0, 0);
}

// ---------------- weight repack: OIHW(int32) -> wq[co][tap*128+ci] i8, bconst
__global__ void repack_w(const int* __restrict__ w, const float* __restrict__ bias,
                         signed char* __restrict__ wq, float* __restrict__ bconst) {
  int co = blockIdx.x;    // 256
  int ci = threadIdx.x;   // 128
  const int* wrow = w + (size_t)co * K_TOT + (size_t)ci * 9;
  int s = 0;
  signed char vals[9];
#pragma unroll
  for (int t = 0; t < 9; ++t) { int v = wrow[t]; vals[t] = (signed char)v; s += v; }
#pragma unroll
  for (int t = 0; t < 9; ++t) wq[(size_t)co * K_TOT + t * 128 + ci] = vals[t];

  __shared__ int red[128];
  red[ci] = s;
  __syncthreads();
  for (int off = 64; off > 0; off >>= 1) {
    if (ci < off) red[ci] += red[ci + off];
    __syncthreads();
  }
  if (ci == 0) {
    int wsum = red[0];
    float r = rintf(bias[co] / 0.0001f);                 // round half-even
    r = fminf(fmaxf(r, -2147483648.0f), 2147483647.0f);  // clamp to i32 range
    float bq = r * 0.0001f;
    bconst[co] = 1e-4f * (float)(-7 * wsum + 24192) + bq;
  }
}

// ---------------- input repack: NCHW(int32) -> NHWC int8
__global__ void repack_in(const int* __restrict__ in, signed char* __restrict__ ip) {
  int h  = blockIdx.x;    // 56
  int n  = blockIdx.y;    // 32
  int ci = threadIdx.x;   // 128
  const int4* src = (const int4*)(in + (((size_t)n * C_IN + ci) * H_IN + h) * W_IN);
  signed char* dst = ip + (((size_t)n * H_IN + h) * W_IN) * C_IN + ci;
#pragma unroll
  for (int i = 0; i < 14; ++i) {
    int4 v = src[i];
    dst[(size_t)(i * 4 + 0) * C_IN] = (signed char)v.x;
    dst[(size_t)(i * 4 + 1) * C_IN] = (signed char)v.y;
    dst[(size_t)(i * 4 + 2) * C_IN] = (signed char)v.z;
    dst[(size_t)(i * 4 + 3) * C_IN] = (signed char)v.w;
  }
}

// ---------------- per-input-pixel channel sums
__global__ void rowsum_k(const signed char* __restrict__ ip, int* __restrict__ rs) {
  int h = blockIdx.x;     // 56
  int n = blockIdx.y;     // 32
  int w = threadIdx.x;    // 64, 56 active
  if (w >= W_IN) return;
  const int4* p = (const int4*)(ip + (((size_t)n * H_IN + h) * W_IN + w) * C_IN);
  int s = 0;
#pragma unroll
  for (int i = 0; i < 8; ++i) {
    int4 v = p[i];
    s = dot4(v.x, 0x01010101, s);
    s = dot4(v.y, 0x01010101, s);
    s = dot4(v.z, 0x01010101, s);
    s = dot4(v.w, 0x01010101, s);
  }
  rs[((size_t)n * H_IN + h) * W_IN + w] = s;
}

// ---------------- per-output-pixel: asumf = -3e-4 * rf-sum, lut = out dword off (co=0)
__global__ void asum_lut(const int* __restrict__ rs, float* __restrict__ asumf,
                         int* __restrict__ lutdw) {
  int px = blockIdx.x * 256 + threadIdx.x;
  if (px >= NPX) return;
  int n = px / PXROW, rem = px - n * PXROW;
  int y = rem / W_OUT, x = rem - y * W_OUT;
  const int* rp = rs + ((size_t)n * H_IN + y) * W_IN + x;
  int s = 0;
#pragma unroll
  for (int kh = 0; kh < 3; ++kh)
    s += rp[kh * W_IN + 0] + rp[kh * W_IN + 1] + rp[kh * W_IN + 2];
  asumf[px] = -3e-4f * (float)s;
  lutdw[px] = n * (C_OUT * PXROW) + y * W_OUT + x;
}

// ---------------- main MFMA conv
// grid 729 (px tiles of 128), block 256 (4 waves). BM=256 co, BN=128 px, 18 K-steps of 64.
// LDS: A dbuf 2x16KB  layout [q(4)][co(256)][16B]
//      B dbuf 2x8KB   layout [q(4)][px(128)][16B]
__launch_bounds__(256, 2)
__global__ void conv_mfma(const signed char* __restrict__ ip,
                          const signed char* __restrict__ wq,
                          const float* __restrict__ asumf,
                          const int* __restrict__ lutdw,
                          const float* __restrict__ bconst,
                          float* __restrict__ out) {
  __shared__ signed char lds[49152];  // A: [0,32768), B: [32768,49152)
  const int tid = threadIdx.x;
  const int w = tid >> 6, l = tid & 63;
  const int pxb = blockIdx.x * 128;

  // staging source bases (per-lane)
  const signed char* asrc = wq + (size_t)(64 * w + l) * K_TOT;  // co row = 64w+l
  const signed char* bsrc[2];
#pragma unroll
  for (int jj = 0; jj < 2; ++jj) {
    int px = pxb + jj * 64 + l;
    int n = px / PXROW, rem = px - n * PXROW;
    int y = rem / W_OUT, x = rem - y * W_OUT;
    bsrc[jj] = ip + ((size_t)(n * H_IN + y) * W_IN + x) * C_IN;
  }

  i32x4 acc[4][8];
#pragma unroll
  for (int m = 0; m < 4; ++m)
#pragma unroll
    for (int p = 0; p < 8; ++p) acc[m][p] = (i32x4){0, 0, 0, 0};

  // ---- stage step 0 into buffer 0 (t=0: tap 0, half 0 -> offset 0)
#pragma unroll
  for (int ii = 0; ii < 4; ++ii)
    gload16(asrc + ii * 16, &lds[ii * 4096 + w * 1024]);
#pragma unroll
  for (int jj = 0; jj < 2; ++jj)
    gload16(bsrc[jj] + w * 16, &lds[32768 + w * 2048 + jj * 1024]);
  __syncthreads();  // emits vmcnt(0) lgkmcnt(0) drain

  // fragment read offsets (lane-constant)
  const int qa = (l >> 4) * 4096 + (64 * w + (l & 15)) * 16;
  const int qb = (l >> 4) * 2048 + (l & 15) * 16;

#pragma unroll
  for (int t = 0; t < 18; ++t) {
    const int cb = t & 1, nb = (t + 1) & 1;
    if (t < 17) {  // stage step t+1 into buffer nb
      const signed char* ap = asrc + (t + 1) * 64;
#pragma unroll
      for (int ii = 0; ii < 4; ++ii)
        gload16(ap + ii * 16, &lds[nb * 16384 + ii * 4096 + w * 1024]);
      int tap = (t + 1) >> 1, half = (t + 1) & 1;
      int boff = ((tap / 3) * W_IN + (tap % 3)) * C_IN + half * 64 + w * 16;
#pragma unroll
      for (int jj = 0; jj < 2; ++jj)
        gload16(bsrc[jj] + boff, &lds[32768 + nb * 8192 + w * 2048 + jj * 1024]);
    }
    // fragment reads (conflict-free: 16-lane groups read contiguous 256B)
    const signed char* Ab = &lds[cb * 16384];
    const signed char* Bb = &lds[32768 + cb * 8192];
    i32x4 af[4], bf[8];
#pragma unroll
    for (int m = 0; m < 4; ++m) af[m] = *(const i32x4*)(Ab + qa + m * 256);
#pragma unroll
    for (int p = 0; p < 8; ++p) bf[p] = *(const i32x4*)(Bb + qb + p * 256);
#pragma unroll
    for (int m = 0; m < 4; ++m)
#pragma unroll
      for (int p = 0; p < 8; ++p)
        acc[m][p] = __builtin_amdgcn_mfma_i32_16x16x64_i8(af[m], bf[p], acc[m][p], 0, 0, 0);
    __syncthreads();  // staging for nb complete + reads of cb retired
  }

  // ---- epilogue: C frag (16x16): col px = lane&15, row co = (lane>>4)*4 + j
  const int colpx = pxb + (l & 15);
  int lut[8]; float asf[8];
#pragma unroll
  for (int p = 0; p < 8; ++p) {
    lut[p] = lutdw[colpx + 16 * p];
    asf[p] = asumf[colpx + 16 * p];
  }
#pragma unroll
  for (int m = 0; m < 4; ++m) {
#pragma unroll
    for (int j = 0; j < 4; ++j) {
      int co = 64 * w + 16 * m + (l >> 4) * 4 + j;
      float bc = bconst[co];
      float* ob = out + (size_t)co * PXROW;
#pragma unroll
      for (int p = 0; p < 8; ++p)
        ob[lut[p]] = 1e-4f * (float)acc[m][p][j] + asf[p] + bc;
    }
  }
}

// ---------------- fallback (tiny ws): naive direct conv
__global__ void conv_naive(const int* __restrict__ in, const int* __restrict__ w,
                           const float* __restrict__ bias, float* __restrict__ out) {
  size_t idx = (size_t)blockIdx.x * 256 + threadIdx.x;
  size_t total = (size_t)N_B * C_OUT * H_OUT * W_OUT;
  if (idx >= total) return;
  int x = idx % W_OUT; size_t t = idx / W_OUT;
  int y = t % H_OUT; t /= H_OUT;
  int co = t % C_OUT; int n = (int)(t / C_OUT);
  int acc = 0;
  for (int ci = 0; ci < C_IN; ++ci) {
    const int* ib = in + (((size_t)n * C_IN + ci) * H_IN + y) * W_IN + x;
    const int* wb = w + (((size_t)co * C_IN + ci) * 3) * 3;
    for (int kh = 0; kh < 3; ++kh)
      for (int kw = 0; kw < 3; ++kw)
        acc += (ib[kh * W_IN + kw] - 7) * (wb[kh * 3 + kw] - 3);
  }
  float r = rintf(bias[co] / 0.0001f);
  r = fminf(fmaxf(r, -2147483648.0f), 2147483647.0f);
  out[idx] = (float)acc * (0.01f * 0.01f) + r * 0.0001f;
}

extern "C" void kernel_launch(void* const* d_in, const int* in_sizes, int n_in,
                              void* d_out, int out_size, void* d_ws, size_t ws_size,
                              hipStream_t stream) {
  const int*   in   = (const int*)d_in[0];
  const int*   w    = (const int*)d_in[1];
  const float* bias = (const float*)d_in[2];
  float*       out  = (float*)d_out;

  // ws layout
  const size_t WQ_OFF = 0;                        // 256*1152 i8      = 294912
  const size_t IP_OFF = 294912;                   // 32*56*56*128 i8  = 12845056
  const size_t RS_OFF = IP_OFF + 12845056;        // 32*56*56 i32     = 401408
  const size_t AF_OFF = RS_OFF + 401408;          // 93312 f32        = 373248
  const size_t LU_OFF = AF_OFF + 373248;          // 93312 i32        = 373248
  const size_t BC_OFF = LU_OFF + 373248;          // 256 f32
  const size_t NEED   = BC_OFF + 1024;

  if (ws_size >= NEED) {
    char* ws = (char*)d_ws;
    signed char* wq   = (signed char*)(ws + WQ_OFF);
    signed char* ip   = (signed char*)(ws + IP_OFF);
    int*         rs   = (int*)(ws + RS_OFF);
    float*       af   = (float*)(ws + AF_OFF);
    int*         lu   = (int*)(ws + LU_OFF);
    float*       bc   = (float*)(ws + BC_OFF);

    repack_w<<<C_OUT, 128, 0, stream>>>(w, bias, wq, bc);
    repack_in<<<dim3(H_IN, N_B), 128, 0, stream>>>(in, ip);
    rowsum_k<<<dim3(H_IN, N_B), 64, 0, stream>>>(ip, rs);
    asum_lut<<<(NPX + 255) / 256, 256, 0, stream>>>(rs, af, lu);
    conv_mfma<<<NPX / 128, 256, 0, stream>>>(ip, wq, af, lu, bc, out);
  } else {
    size_t total = (size_t)N_B * C_OUT * H_OUT * W_OUT;
    conv_naive<<<(total + 255) / 256, 256, 0, stream>>>(in, w, bias, out);
  }
}